// Round 17
// baseline (60.990 us; speedup 1.0000x reference)
//
#include <hip/hip_runtime.h>

#define B 4
#define C 19
#define H 192
#define W 192
#define HW (H * W)
#define NP (B * C)
// 40 / ln(2): exp(-40*x) == exp2(-THETA_LOG2E*x)
#define THETA_LOG2E 57.70780163555855f

#define NCOL 228          // col-role blocks (NP * 3)
#define NROW 912          // row-role blocks (8 waves x 2 rows each -> 16 rows/block)
#define RSTRIDE 7296      // NROW * 8

// k_first extra roles
#define C1_BEG (NCOL + NROW)        // 1140: dT transpose, 144 blocks
#define C2_BEG (C1_BEG + 144)       // 1284: dcol (N+T), 12 blocks
#define C3_BEG (C2_BEG + 12)        // 1296: drow (N+T), 12 blocks
#define NFIRST (C3_BEG + 12)        // 1308

// bf16 helpers (RNE)
__device__ __forceinline__ unsigned short f2b(float x) {
    unsigned u = __float_as_uint(x);
    u = (u + 0x7FFFu + ((u >> 16) & 1u)) >> 16;
    return (unsigned short)u;
}
__device__ __forceinline__ float b2f(unsigned short h) {
    return __uint_as_float(((unsigned)h) << 16);
}

// in-wave bidirectional first-order scan over 192 elems (3/lane), proven R11 math.
// d3 MUST be 0 for lane 63.  Z[s]=d[s]Z[s-1]+f[s];  S[s]=d[s+1]S[s+1]+f[s].
__device__ __forceinline__ void ks_scan(int lane, float f0, float f1, float f2v,
                                        float d0, float d1, float d2, float d3,
                                        float& zA, float& zB, float& zC,
                                        float& sA, float& sB, float& sC) {
    float P = d0 * d1 * d2;
    float Q = (f0 * d1 + f1) * d2 + f2v;
    #pragma unroll
    for (int off = 1; off < 64; off <<= 1) {
        float Pp = __shfl_up(P, off), Qp = __shfl_up(Q, off);
        if (lane >= off) { Q = Qp * P + Q; P = Pp * P; }
    }
    float zin = __shfl_up(Q, 1);
    if (lane == 0) zin = 0.f;
    zA = zin * d0 + f0; zB = zA * d1 + f1; zC = zB * d2 + f2v;
    float Pb = d3 * d2 * d1;
    float Qb = (f2v * d2 + f1) * d1 + f0;
    #pragma unroll
    for (int off = 1; off < 64; off <<= 1) {
        float Pp = __shfl_down(Pb, off), Qp = __shfl_down(Qb, off);
        if (lane < 64 - off) { Qb = Qp * Pb + Qb; Pb = Pp * Pb; }
    }
    float sin_ = __shfl_down(Qb, 1);
    if (lane == 63) sin_ = 0.f;
    sC = sin_ * d3 + f2v; sB = sC * d2 + f1; sA = sB * d1 + f0;
}

// ================= launch 1: cs0, rs0 + all edge-derived constants =================
__global__ __launch_bounds__(512) void k_first(const float* __restrict__ mask,
                                               const float* __restrict__ edge,
                                               unsigned short* __restrict__ csA,
                                               unsigned short* __restrict__ rsA,
                                               float* __restrict__ dT,
                                               float* __restrict__ dcolN,
                                               float* __restrict__ drowN,
                                               float* __restrict__ dcolT,
                                               float* __restrict__ drowT) {
    __shared__ float tf[192 * 65];          // 49.9 KB (f32 tile / stage)
    __shared__ unsigned short tu[192 * 66]; // 25.3 KB (bf16 tile)
    const int t = threadIdx.x, lane = t & 63, wave = t >> 6;
    const int bx = blockIdx.x;

    if (bx < NCOL) {
        // ---- col role MODE0: cs0 = colscan(mask) for [plane p, 64 cols] ----
        int jt = bx % 3, p = bx / 3, b = p / C;
        #pragma unroll
        for (int k = 0; k < 12; ++k) {
            int e = t + k * 512; int i = e >> 5, jp = e & 31;
            float2 mv = *(const float2*)&mask[(size_t)p * HW + i * W + jt * 64 + 2 * jp];
            ((unsigned*)tu)[33 * i + jp] = (unsigned)f2b(mv.x) | ((unsigned)f2b(mv.y) << 16);
            float2 ev = *(const float2*)&edge[(size_t)b * HW + i * W + jt * 64 + 2 * jp];
            tf[65 * i + 2 * jp]     = exp2f(-THETA_LOG2E * fmaxf(ev.x, 0.f));
            tf[65 * i + 2 * jp + 1] = exp2f(-THETA_LOG2E * fmaxf(ev.y, 0.f));
        }
        __syncthreads();
        #pragma unroll
        for (int q = 0; q < 8; ++q) {
            int jl = wave * 8 + q;
            int r0 = 3 * lane;
            float f0 = b2f(tu[r0 * 66 + jl]), f1 = b2f(tu[(r0 + 1) * 66 + jl]), f2v = b2f(tu[(r0 + 2) * 66 + jl]);
            float d0 = tf[r0 * 65 + jl], d1 = tf[(r0 + 1) * 65 + jl], d2 = tf[(r0 + 2) * 65 + jl];
            float d3 = (lane < 63) ? tf[(r0 + 3) * 65 + jl] : 0.f;
            float zA, zB, zC, sA, sB, sC;
            ks_scan(lane, f0, f1, f2v, d0, d1, d2, d3, zA, zB, zC, sA, sB, sC);
            tu[r0 * 66 + jl]       = f2b(zA + sA - f0);    // diag counted once
            tu[(r0 + 1) * 66 + jl] = f2b(zB + sB - f1);
            tu[(r0 + 2) * 66 + jl] = f2b(zC + sC - f2v);
        }
        __syncthreads();
        #pragma unroll
        for (int k = 0; k < 12; ++k) {
            int e = t + k * 512; int i = e >> 5, jp = e & 31;
            *(unsigned*)&csA[(size_t)p * HW + i * W + jt * 64 + 2 * jp] = ((unsigned*)tu)[33 * i + jp];
        }
    } else if (bx < NCOL + NROW) {
        // ---- row role MODE0: rs0 = rowscan(mask) - 2f, 2 rows per wave ----
        int rblk = bx - NCOL;
        #pragma unroll
        for (int k = 0; k < 2; ++k) {
            int rr = rblk * 8 + wave + k * RSTRIDE;
            int i = rr % H, c = (rr / H) % C, b = rr / (H * C);
            size_t rb = (size_t)(b * C + c) * HW + (size_t)i * W;
            size_t db = (size_t)b * HW + (size_t)i * W;
            int s0 = 3 * lane;
            float d0 = exp2f(-THETA_LOG2E * fmaxf(edge[db + s0], 0.f));
            float d1 = exp2f(-THETA_LOG2E * fmaxf(edge[db + s0 + 1], 0.f));
            float d2 = exp2f(-THETA_LOG2E * fmaxf(edge[db + s0 + 2], 0.f));
            float d3 = 0.f;
            if (lane < 63) d3 = exp2f(-THETA_LOG2E * fmaxf(edge[db + s0 + 3], 0.f));
            float f0 = mask[rb + s0], f1 = mask[rb + s0 + 1], f2v = mask[rb + s0 + 2];
            float zA, zB, zC, sA, sB, sC;
            ks_scan(lane, f0, f1, f2v, d0, d1, d2, d3, zA, zB, zC, sA, sB, sC);
            rsA[rb + s0]     = f2b(zA + sA - 2.f * f0);
            rsA[rb + s0 + 1] = f2b(zB + sB - 2.f * f1);
            rsA[rb + s0 + 2] = f2b(zC + sC - 2.f * f2v);
        }
    } else if (bx < C2_BEG) {
        // ---- role c1: dT[b][j][i] = exp2(-theta*relu(edge[i][j])) (transpose) ----
        int blk = bx - C1_BEG;
        int tx = blk % 6, ty = (blk / 6) % 6, b = blk / 36;
        if (t < 256) {
            int lx = t % 32, ly = t / 32;
            #pragma unroll
            for (int k = 0; k < 4; ++k) {
                int il = ly + k * 8;
                int I = ty * 32 + il, J = tx * 32 + lx;
                float e = edge[(b * H + I) * W + J];
                tf[il * 33 + lx] = exp2f(-THETA_LOG2E * fmaxf(e, 0.f));
            }
        }
        __syncthreads();
        if (t < 256) {
            int lx = t % 32, ly = t / 32;
            #pragma unroll
            for (int k = 0; k < 4; ++k) {
                int jl = ly + k * 8;
                dT[((size_t)b * W + tx * 32 + jl) * H + ty * 32 + lx] = tf[lx * 33 + jl];
            }
        }
    } else if (bx < C3_BEG) {
        // ---- role c2: dcolN + dcolT (unit-f column scans via KS) ----
        int bb = bx - C2_BEG; int jt = bb % 3, b = bb / 3;
        #pragma unroll
        for (int k = 0; k < 12; ++k) {
            int e = t + k * 512; int i = e >> 5, jp = e & 31;
            float2 ev = *(const float2*)&edge[(size_t)b * HW + i * W + jt * 64 + 2 * jp];
            tf[65 * i + 2 * jp]     = exp2f(-THETA_LOG2E * fmaxf(ev.x, 0.f));
            tf[65 * i + 2 * jp + 1] = exp2f(-THETA_LOG2E * fmaxf(ev.y, 0.f));
        }
        __syncthreads();
        #pragma unroll
        for (int q = 0; q < 8; ++q) {
            int jl = wave * 8 + q;
            int j = jt * 64 + jl;
            int r0 = 3 * lane;
            float d0 = tf[r0 * 65 + jl], d1 = tf[(r0 + 1) * 65 + jl], d2 = tf[(r0 + 2) * 65 + jl];
            float d3 = (lane < 63) ? tf[(r0 + 3) * 65 + jl] : 0.f;
            float zA, zB, zC, sA, sB, sC;
            ks_scan(lane, 1.f, 1.f, 1.f, d0, d1, d2, d3, zA, zB, zC, sA, sB, sC);
            float uA = zA + sA - 1.f, uB = zB + sB - 1.f, uC = zC + sC - 1.f;
            size_t tb = ((size_t)b * W + j) * H + r0;
            dcolT[tb] = uA; dcolT[tb + 1] = uB; dcolT[tb + 2] = uC;
            tf[r0 * 65 + jl] = uA; tf[(r0 + 1) * 65 + jl] = uB; tf[(r0 + 2) * 65 + jl] = uC;
        }
        __syncthreads();
        #pragma unroll
        for (int k = 0; k < 24; ++k) {
            int e = t + k * 512; int i = e >> 6, jl = e & 63;
            dcolN[(size_t)b * HW + i * W + jt * 64 + jl] = tf[65 * i + jl];
        }
    } else {
        // ---- role c3: drowN + drowT (unit-f row scans via KS), 64 rows/block ----
        int bb = bx - C3_BEG; int b = bb / 3, i0 = (bb % 3) * 64;
        #pragma unroll
        for (int k = 0; k < 8; ++k) {
            int il = wave * 8 + k;
            int i = i0 + il;
            size_t db = (size_t)b * HW + (size_t)i * W;
            int s0 = 3 * lane;
            float d0 = exp2f(-THETA_LOG2E * fmaxf(edge[db + s0], 0.f));
            float d1 = exp2f(-THETA_LOG2E * fmaxf(edge[db + s0 + 1], 0.f));
            float d2 = exp2f(-THETA_LOG2E * fmaxf(edge[db + s0 + 2], 0.f));
            float d3 = 0.f;
            if (lane < 63) d3 = exp2f(-THETA_LOG2E * fmaxf(edge[db + s0 + 3], 0.f));
            float zA, zB, zC, sA, sB, sC;
            ks_scan(lane, 1.f, 1.f, 1.f, d0, d1, d2, d3, zA, zB, zC, sA, sB, sC);
            float uA = zA + sA - 1.f, uB = zB + sB - 1.f, uC = zC + sC - 1.f;
            drowN[db + s0] = uA; drowN[db + s0 + 1] = uB; drowN[db + s0 + 2] = uC;
            tf[il * 193 + s0] = uA; tf[il * 193 + s0 + 1] = uB; tf[il * 193 + s0 + 2] = uC;
        }
        __syncthreads();
        #pragma unroll
        for (int k = 0; k < 24; ++k) {
            int e = t + k * 512; int j = e >> 6, il = e & 63;   // 64*192 elems
            drowT[((size_t)b * W + j) * H + i0 + il] = tf[il * 193 + j];
        }
    }
}

// ================= iteration launch (MODE1): fold + scans, both roles =================
__global__ __launch_bounds__(512) void k_iter2(const unsigned short* __restrict__ csin,
                                               const unsigned short* __restrict__ rsin,
                                               unsigned short* __restrict__ csout,
                                               unsigned short* __restrict__ rsout,
                                               const float* __restrict__ edge,
                                               const float* __restrict__ dT,
                                               const float* __restrict__ dcolN,
                                               const float* __restrict__ drowN,
                                               const float* __restrict__ dcolT,
                                               const float* __restrict__ drowT) {
    __shared__ unsigned short tcs[192 * 66], trs[192 * 66];   // 50.7 KB
    const int t = threadIdx.x, lane = t & 63, wave = t >> 6;
    const int bx = blockIdx.x;

    if (bx < NCOL) {
        // ---- col role: cs_k = colscan(f), f = (cs+rs)/(dcol+drow-1) ----
        int jt = bx % 3, p = bx / 3, b = p / C;
        #pragma unroll
        for (int k = 0; k < 12; ++k) {
            int e = t + k * 512; int i = e >> 5, jp = e & 31;
            size_t g = (size_t)p * HW + i * W + jt * 64 + 2 * jp;
            ((unsigned*)tcs)[33 * i + jp] = *(const unsigned*)&csin[g];
            ((unsigned*)trs)[33 * i + jp] = *(const unsigned*)&rsin[g];
        }
        __syncthreads();
        #pragma unroll
        for (int q = 0; q < 8; ++q) {
            int jl = wave * 8 + q;
            int j = jt * 64 + jl;
            int r0 = 3 * lane;
            size_t tb = ((size_t)b * W + j) * H + r0;
            float rd0 = 1.f / (dcolT[tb]     + drowT[tb]     - 1.f);
            float rd1 = 1.f / (dcolT[tb + 1] + drowT[tb + 1] - 1.f);
            float rd2 = 1.f / (dcolT[tb + 2] + drowT[tb + 2] - 1.f);
            float f0 = (b2f(tcs[r0 * 66 + jl])       + b2f(trs[r0 * 66 + jl]))       * rd0;
            float f1 = (b2f(tcs[(r0 + 1) * 66 + jl]) + b2f(trs[(r0 + 1) * 66 + jl])) * rd1;
            float f2v = (b2f(tcs[(r0 + 2) * 66 + jl]) + b2f(trs[(r0 + 2) * 66 + jl])) * rd2;
            float d0 = dT[tb], d1 = dT[tb + 1], d2 = dT[tb + 2];
            float d3 = (lane < 63) ? dT[tb + 3] : 0.f;
            float zA, zB, zC, sA, sB, sC;
            ks_scan(lane, f0, f1, f2v, d0, d1, d2, d3, zA, zB, zC, sA, sB, sC);
            tcs[r0 * 66 + jl]       = f2b(zA + sA - f0);
            tcs[(r0 + 1) * 66 + jl] = f2b(zB + sB - f1);
            tcs[(r0 + 2) * 66 + jl] = f2b(zC + sC - f2v);
        }
        __syncthreads();
        #pragma unroll
        for (int k = 0; k < 12; ++k) {
            int e = t + k * 512; int i = e >> 5, jp = e & 31;
            *(unsigned*)&csout[(size_t)p * HW + i * W + jt * 64 + 2 * jp] = ((unsigned*)tcs)[33 * i + jp];
        }
    } else {
        // ---- row role: rs_k = rowscan(f) - 2f ----
        int rblk = bx - NCOL;
        #pragma unroll
        for (int k = 0; k < 2; ++k) {
            int rr = rblk * 8 + wave + k * RSTRIDE;
            int i = rr % H, c = (rr / H) % C, b = rr / (H * C);
            size_t rb = (size_t)(b * C + c) * HW + (size_t)i * W;
            size_t db = (size_t)b * HW + (size_t)i * W;
            int s0 = 3 * lane;
            float d0 = exp2f(-THETA_LOG2E * fmaxf(edge[db + s0], 0.f));
            float d1 = exp2f(-THETA_LOG2E * fmaxf(edge[db + s0 + 1], 0.f));
            float d2 = exp2f(-THETA_LOG2E * fmaxf(edge[db + s0 + 2], 0.f));
            float d3 = 0.f;
            if (lane < 63) d3 = exp2f(-THETA_LOG2E * fmaxf(edge[db + s0 + 3], 0.f));
            float rd0 = 1.f / (dcolN[db + s0]     + drowN[db + s0]     - 1.f);
            float rd1 = 1.f / (dcolN[db + s0 + 1] + drowN[db + s0 + 1] - 1.f);
            float rd2 = 1.f / (dcolN[db + s0 + 2] + drowN[db + s0 + 2] - 1.f);
            float f0 = (b2f(csin[rb + s0])     + b2f(rsin[rb + s0]))     * rd0;
            float f1 = (b2f(csin[rb + s0 + 1]) + b2f(rsin[rb + s0 + 1])) * rd1;
            float f2v = (b2f(csin[rb + s0 + 2]) + b2f(rsin[rb + s0 + 2])) * rd2;
            float zA, zB, zC, sA, sB, sC;
            ks_scan(lane, f0, f1, f2v, d0, d1, d2, d3, zA, zB, zC, sA, sB, sC);
            rsout[rb + s0]     = f2b(zA + sA - 2.f * f0);
            rsout[rb + s0 + 1] = f2b(zB + sB - 2.f * f1);
            rsout[rb + s0 + 2] = f2b(zC + sC - 2.f * f2v);
        }
    }
}

// ================= final combine: out = (cs + rs) / (dcol + drow - 1) =================
__global__ __launch_bounds__(256) void k_comb(const unsigned short* __restrict__ cs,
                                              const unsigned short* __restrict__ rs,
                                              const float* __restrict__ dcolN,
                                              const float* __restrict__ drowN,
                                              float* __restrict__ out) {
    int idx4 = (blockIdx.x * 256 + threadIdx.x) * 4;
    int p = idx4 / HW;
    int rem = idx4 - p * HW;
    int b = p / C;
    size_t db = (size_t)b * HW + rem;
    uint2 csu = *(const uint2*)(cs + idx4);
    uint2 rsu = *(const uint2*)(rs + idx4);
    float4 dc = *(const float4*)(dcolN + db);
    float4 dw = *(const float4*)(drowN + db);
    float4 o;
    o.x = (b2f((unsigned short)(csu.x & 0xffff)) + b2f((unsigned short)(rsu.x & 0xffff))) / (dc.x + dw.x - 1.f);
    o.y = (b2f((unsigned short)(csu.x >> 16))    + b2f((unsigned short)(rsu.x >> 16)))    / (dc.y + dw.y - 1.f);
    o.z = (b2f((unsigned short)(csu.y & 0xffff)) + b2f((unsigned short)(rsu.y & 0xffff))) / (dc.z + dw.z - 1.f);
    o.w = (b2f((unsigned short)(csu.y >> 16))    + b2f((unsigned short)(rsu.y >> 16)))    / (dc.w + dw.w - 1.f);
    *(float4*)(out + idx4) = o;
}

extern "C" void kernel_launch(void* const* d_in, const int* in_sizes, int n_in,
                              void* d_out, int out_size, void* d_ws, size_t ws_size,
                              hipStream_t stream) {
    const float* mask = (const float*)d_in[0];
    const float* edge = (const float*)d_in[1];
    float* out = (float*)d_out;

    float* dT    = (float*)d_ws;                    // [B,W,H]
    float* dcolN = dT + (size_t)B * HW;             // [B,H,W]
    float* drowN = dcolN + (size_t)B * HW;          // [B,H,W]
    float* dcolT = drowN + (size_t)B * HW;          // [B,W,H]
    float* drowT = dcolT + (size_t)B * HW;          // [B,W,H]
    unsigned short* csA = (unsigned short*)(drowT + (size_t)B * HW);
    unsigned short* rsA = csA + (size_t)NP * HW;    // bf16 [NP,H,W] each
    unsigned short* csB = rsA + (size_t)NP * HW;
    unsigned short* rsB = csB + (size_t)NP * HW;

    // L1: cs0, rs0 + dT/dcol/drow (N and T)
    k_first<<<NFIRST, 512, 0, stream>>>(mask, edge, csA, rsA, dT, dcolN, drowN, dcolT, drowT);
    // L2: fold A -> B
    k_iter2<<<NCOL + NROW, 512, 0, stream>>>(csA, rsA, csB, rsB, edge, dT, dcolN, drowN, dcolT, drowT);
    // L3: fold B -> A
    k_iter2<<<NCOL + NROW, 512, 0, stream>>>(csB, rsB, csA, rsA, edge, dT, dcolN, drowN, dcolT, drowT);
    // final combine
    k_comb<<<(NP * HW) / (4 * 256), 256, 0, stream>>>(csA, rsA, dcolN, drowN, out);
}